// Round 12
// baseline (259.570 us; speedup 1.0000x reference)
//
#include <hip/hip_runtime.h>
#include <math.h>

#define N_NODES 50000
#define N_EDGES 800000
#define F_IN    512
#define H1      8
#define F_HID   8
#define C1      64      // H1*F_HID
#define NLAB    64
#define SLOPE   0.2f
#define MAXDEG  64      // multinomial(800K,50K): mean 16, max ~35; 64 is safe

#define NBIN    98      // coarse node bins of 512 nodes (98*512 = 50176)
#define BINCAP  9216    // per-bin edge capacity: mean 8163 -> +11 sigma
#define NBLK_WT  128    // W1-split tasks (256 thr)
#define NBLK_E   391    // edge-binning tasks (2048 edges each; 391*2048 >= 800000)
#define NBLK_G1  782    // gemm1 row-blocks (64 rows each)
#define NCHUNK  1563    // 32-node agg chunks

typedef __attribute__((ext_vector_type(8))) short short8;
typedef __attribute__((ext_vector_type(4))) float f32x4;

__device__ __forceinline__ float bf_lo(unsigned u) { return __uint_as_float(u << 16); }
__device__ __forceinline__ float bf_hi(unsigned u) { return __uint_as_float(u & 0xFFFF0000u); }
__device__ __forceinline__ unsigned short f2bf(float x) {
    unsigned bits = __float_as_uint(x);
    return (unsigned short)((bits + 0x7FFF + ((bits >> 16) & 1)) >> 16);   // RNE
}

// ------- prep: W1 bf16 split (blocks 0..127) + edge binning (128..518, 2048 edges) -------
__global__ void k_prepbin(const float* __restrict__ W1, unsigned short* __restrict__ Bh,
                          unsigned short* __restrict__ Bl,
                          const int* __restrict__ src, const int* __restrict__ dst,
                          unsigned* __restrict__ ebuf, int* __restrict__ gctr) {
    const int b = blockIdx.x;
    const int t = threadIdx.x;
    if (b < NBLK_WT) {
        int i = b * 256 + t;   // 0..32767
        int c = i >> 9, f = i & 511;
        float v = W1[(c >> 3) * (F_IN * F_HID) + f * F_HID + (c & 7)];
        unsigned bits = __float_as_uint(v);
        float r = v - __uint_as_float(bits & 0xFFFF0000u);
        Bh[i] = (unsigned short)(bits >> 16);
        Bl[i] = (unsigned short)(__float_as_uint(r) >> 16);
        return;
    }
    __shared__ int hist[NBIN];
    __shared__ int cur[NBIN];
    if (t < NBIN) hist[t] = 0;
    __syncthreads();
    int4 dv[2], sv[2];
    const int e0 = (b - NBLK_WT) * 2048 + t * 4;
    #pragma unroll
    for (int i = 0; i < 2; i++) {
        int e = e0 + i * 1024;
        if (e < N_EDGES) {
            dv[i] = *(const int4*)(dst + e);
            sv[i] = *(const int4*)(src + e);
            atomicAdd(&hist[dv[i].x >> 9], 1);
            atomicAdd(&hist[dv[i].y >> 9], 1);
            atomicAdd(&hist[dv[i].z >> 9], 1);
            atomicAdd(&hist[dv[i].w >> 9], 1);
        }
    }
    __syncthreads();
    if (t < NBIN) cur[t] = atomicAdd(&gctr[t], hist[t]);
    __syncthreads();
    #pragma unroll
    for (int i = 0; i < 2; i++) {
        int e = e0 + i * 1024;
        if (e < N_EDGES) {
            int d, s, sl;
            d = dv[i].x; s = sv[i].x; sl = atomicAdd(&cur[d >> 9], 1);
            ebuf[(size_t)(d >> 9) * BINCAP + min(sl, BINCAP - 1)] = ((unsigned)(d & 511) << 16) | (unsigned)s;
            d = dv[i].y; s = sv[i].y; sl = atomicAdd(&cur[d >> 9], 1);
            ebuf[(size_t)(d >> 9) * BINCAP + min(sl, BINCAP - 1)] = ((unsigned)(d & 511) << 16) | (unsigned)s;
            d = dv[i].z; s = sv[i].z; sl = atomicAdd(&cur[d >> 9], 1);
            ebuf[(size_t)(d >> 9) * BINCAP + min(sl, BINCAP - 1)] = ((unsigned)(d & 511) << 16) | (unsigned)s;
            d = dv[i].w; s = sv[i].w; sl = atomicAdd(&cur[d >> 9], 1);
            ebuf[(size_t)(d >> 9) * BINCAP + min(sl, BINCAP - 1)] = ((unsigned)(d & 511) << 16) | (unsigned)s;
        }
    }
}

// -------- blocks 0..97: per-bin CSR build; 98..879: GEMM1 (256 thr, 64-col K-chunks) ----
// K-chunk 128 -> 64 halves the LDS tile (34.8KB -> 18.4KB): 8 blocks/CU x 4 waves
// = 32 waves/CU, 2x the latency hiding of R9 at the same 256-thread shape.
// K-subchunk order (ascending 32-col groups) is preserved -> results identical.
__launch_bounds__(256, 8)
__global__ void k_g1csr(const float* __restrict__ X, const unsigned short* __restrict__ Bh,
                        const unsigned short* __restrict__ Bl, const float* __restrict__ a1s,
                        const float* __restrict__ a1d, float* __restrict__ es1,
                        unsigned short* __restrict__ wh1, float* __restrict__ ed1,
                        const unsigned* __restrict__ ebuf, const int* __restrict__ gctr,
                        int* __restrict__ deg, unsigned short* __restrict__ colPad) {
    __shared__ __align__(16) char smem[18432];
    const int b = blockIdx.x;
    const int t = threadIdx.x;

    if (b < NBIN) {                // ---- per-bin CSR build ----
        int* cnt = (int*)smem;     // 512 counters (2KB)
        const int lo = b << 9;
        const int cnum = min(gctr[b], BINCAP);
        for (int i = t; i < 512; i += 256) cnt[i] = 0;
        __syncthreads();
        const unsigned* eb2 = ebuf + (size_t)b * BINCAP;
        for (int i = t; i < cnum; i += 256) {
            unsigned e = eb2[i];
            int dl = (int)(e >> 16);
            int sl = atomicAdd(&cnt[dl], 1);       // LDS atomic
            colPad[((size_t)(lo + dl) << 6) | min(sl, MAXDEG - 1)] = (unsigned short)(e & 0xFFFFu);
        }
        __syncthreads();
        for (int i = t; i < 512; i += 256) {
            int n = lo + i;
            if (n < N_NODES) deg[n] = min(cnt[i], MAXDEG);
        }
        return;
    }

    // ---- GEMM1 + es/ed/record pack: 4 waves x 16 rows = 64 rows/block ----
    unsigned short (*sBh)[72] = (unsigned short(*)[72])smem;            // 9216B
    unsigned short (*sBl)[72] = (unsigned short(*)[72])(smem + 9216);   // 9216B
    const int lane = t & 63, w = t >> 6;
    const int r0 = (b - NBIN) * 64 + w * 16;
    const int m = lane & 15, quad = lane >> 4;
    int row = r0 + m; if (row >= N_NODES) row = N_NODES - 1;
    const float* xrow = X + (size_t)row * F_IN + quad * 8;
    const int sc = t >> 2;     // 0..63 (B row)
    const int sp = t & 3;      // 0..3  (16-short segment of 64 cols)

    f32x4 acc[4] = {};
    float4 pxa[2], pxb[2];
    #pragma unroll
    for (int i = 0; i < 2; i++) {
        pxa[i] = *(const float4*)(xrow + i * 32);
        pxb[i] = *(const float4*)(xrow + i * 32 + 4);
    }

    for (int chunk = 0; chunk < 8; chunk++) {
        const int k0 = chunk * 64;
        if (chunk) __syncthreads();
        #pragma unroll
        for (int i = 0; i < 2; i++) {
            *(short8*)(&sBh[sc][sp * 16 + i * 8]) =
                *(const short8*)(Bh + sc * F_IN + k0 + sp * 16 + i * 8);
            *(short8*)(&sBl[sc][sp * 16 + i * 8]) =
                *(const short8*)(Bl + sc * F_IN + k0 + sp * 16 + i * 8);
        }
        __syncthreads();
        #pragma unroll
        for (int i = 0; i < 2; i++) {
            float xs[8] = {pxa[i].x, pxa[i].y, pxa[i].z, pxa[i].w,
                           pxb[i].x, pxb[i].y, pxb[i].z, pxb[i].w};
            if (chunk < 7) {
                const int ktn = k0 + 64 + i * 32;
                pxa[i] = *(const float4*)(xrow + ktn);
                pxb[i] = *(const float4*)(xrow + ktn + 4);
            }
            short8 ah, al;
            #pragma unroll
            for (int j = 0; j < 8; j++) {
                unsigned bits = __float_as_uint(xs[j]);
                float rr = xs[j] - __uint_as_float(bits & 0xFFFF0000u);
                ah[j] = (short)(bits >> 16);
                al[j] = (short)(__float_as_uint(rr) >> 16);
            }
            #pragma unroll
            for (int s = 0; s < 4; s++) {
                short8 bh = *(const short8*)(&sBh[s * 16 + m][i * 32 + quad * 8]);
                short8 bl = *(const short8*)(&sBl[s * 16 + m][i * 32 + quad * 8]);
                acc[s] = __builtin_amdgcn_mfma_f32_16x16x32_bf16(al, bh, acc[s], 0, 0, 0);
                acc[s] = __builtin_amdgcn_mfma_f32_16x16x32_bf16(ah, bl, acc[s], 0, 0, 0);
                acc[s] = __builtin_amdgcn_mfma_f32_16x16x32_bf16(ah, bh, acc[s], 0, 0, 0);
            }
        }
    }
    __syncthreads();
    unsigned short* sWh = (unsigned short*)smem + w * 1024;   // 4 waves x 2KB = 8KB
    #pragma unroll
    for (int s = 0; s < 4; s++)
        #pragma unroll
        for (int reg = 0; reg < 4; reg++)
            sWh[(quad * 4 + reg) * 64 + s * 16 + m] = f2bf(acc[s][reg]);
    __syncthreads();
    const int rr = lane & 15, p = lane >> 4;
    const int n = r0 + rr;
    if (n >= N_NODES) return;
    float es2v[2], edv[2];
    #pragma unroll
    for (int hh = 0; hh < 2; hh++) {
        int h = 2 * p + hh;
        float s = 0.f, dsum = 0.f;
        #pragma unroll
        for (int j = 0; j < 8; j++) {
            float v = __uint_as_float((unsigned)sWh[rr * 64 + h * 8 + j] << 16);
            s += v * a1s[h * 8 + j];
            dsum += v * a1d[h * 8 + j];
        }
        es2v[hh] = s; edv[hh] = dsum;
    }
    *(float2*)(es1 + n * 8 + 2 * p) = make_float2(es2v[0], es2v[1]);
    *(short8*)(wh1 + (size_t)n * 64 + p * 16)     = *(const short8*)(sWh + rr * 64 + p * 16);
    *(short8*)(wh1 + (size_t)n * 64 + p * 16 + 8) = *(const short8*)(sWh + rr * 64 + p * 16 + 8);
    *(float2*)(ed1 + n * 8 + 2 * p) = make_float2(edv[0], edv[1]);
}

// -------- FUSED layer-1 aggregation + GEMM2; ushort scol (28.5KB LDS -> 5 blk/CU) --------
__launch_bounds__(256)
__global__ void k_agg1g2(const float* __restrict__ es1, const unsigned short* __restrict__ wh1,
                         const float* __restrict__ ed1,
                         const int* __restrict__ deg, const unsigned short* __restrict__ colPad,
                         const float* __restrict__ W2, const float* __restrict__ a2s,
                         const float* __restrict__ a2d,
                         float* __restrict__ es2, unsigned short* __restrict__ wh2,
                         float* __restrict__ ed2) {
    __shared__ float Ws[64 * 64];              // 16KB
    __shared__ float hs[32][64];               // 8KB
    __shared__ unsigned short scol[32][72];    // 4.6KB
    const int t = threadIdx.x;
    #pragma unroll
    for (int i = 0; i < 4; i++) {
        int flat = i * 256 + t;
        *(float4*)(Ws + flat * 4) = *(const float4*)(W2 + flat * 4);
    }
    const int n0 = blockIdx.x * 32;
    {   // stage colPad rows: 32 nodes * 8 int4 = 256 int4, one per thread
        size_t gi = (size_t)n0 * 8 + t;
        int4 v = (gi < (size_t)N_NODES * 8) ? ((const int4*)colPad)[gi]
                                            : make_int4(0, 0, 0, 0);
        *(int4*)&scol[t >> 3][(t & 7) * 8] = v;
    }
    __syncthreads();

    const int nl = t >> 3, q = t & 7;
    const int n = n0 + nl;
    float o[8] = {};
    if (n < N_NODES) {
        const int d = deg[n];
        const float edq = ed1[n * 8 + q];
        float den = 0.f;
        float acc[8] = {};
        #pragma unroll 4
        for (int e = 0; e < d; ++e) {
            int sv = scol[nl][e];
            float x = es1[sv * 8 + q] + edq;
            uint4 u = *(const uint4*)(wh1 + (size_t)sv * 64 + q * 8);
            x = x > 0.f ? x : SLOPE * x;
            float wg = __expf(x);
            den += wg;
            acc[0] += wg * bf_lo(u.x); acc[1] += wg * bf_hi(u.x);
            acc[2] += wg * bf_lo(u.y); acc[3] += wg * bf_hi(u.y);
            acc[4] += wg * bf_lo(u.z); acc[5] += wg * bf_hi(u.z);
            acc[6] += wg * bf_lo(u.w); acc[7] += wg * bf_hi(u.w);
        }
        float inv = 1.f / (den + 1e-10f);
        #pragma unroll
        for (int j = 0; j < 8; j++) {
            float v = acc[j] * inv;
            o[j] = v > 0.f ? v : expm1f(v);   // fused ELU
        }
    }
    float4* hp = (float4*)(&hs[nl][q * 8]);
    hp[0] = make_float4(o[0], o[1], o[2], o[3]);
    hp[1] = make_float4(o[4], o[5], o[6], o[7]);
    __syncthreads();

    // ---- GEMM2 phase: wave wv handles 8 nodes, lane = output class ----
    const int wv = t >> 6, lane = t & 63;
    const float as = a2s[lane], ad = a2d[lane];
    #pragma unroll
    for (int j = 0; j < 8; j++) {
        int nn = n0 + wv * 8 + j;
        if (nn >= N_NODES) break;
        float accv = 0.f;
        #pragma unroll
        for (int k = 0; k < 64; k++) accv += hs[wv * 8 + j][k] * Ws[k * 64 + lane];
        wh2[(size_t)nn * 64 + lane] = f2bf(accv);
        float s = accv * as;
        float dd = accv * ad;
        #pragma unroll
        for (int off = 1; off < 64; off <<= 1) {
            s += __shfl_xor(s, off);
            dd += __shfl_xor(dd, off);
        }
        if (lane == 0) { es2[nn] = s; ed2[nn] = dd; }
    }
}

// ------- layer-2 aggregation + fused final softmax; ushort scol -------
__launch_bounds__(256)
__global__ void k_agg2(const float* __restrict__ es2, const unsigned short* __restrict__ wh2,
                       const float* __restrict__ ed2,
                       const int* __restrict__ deg, const unsigned short* __restrict__ colPad,
                       float* __restrict__ out) {
    __shared__ unsigned short scol[32][72];
    const int t = threadIdx.x;
    const int n0 = blockIdx.x * 32;
    {
        size_t gi = (size_t)n0 * 8 + t;
        int4 v = (gi < (size_t)N_NODES * 8) ? ((const int4*)colPad)[gi]
                                            : make_int4(0, 0, 0, 0);
        *(int4*)&scol[t >> 3][(t & 7) * 8] = v;
    }
    __syncthreads();

    const int nl = t >> 3, q = t & 7;
    const int n = n0 + nl;
    if (n >= N_NODES) return;
    const int d = deg[n];
    const float edn = ed2[n];

    float den = 0.f;
    float acc[8] = {};
    #pragma unroll 4
    for (int e = 0; e < d; ++e) {
        int sv = scol[nl][e];
        float x = es2[sv] + edn;
        uint4 u = *(const uint4*)(wh2 + (size_t)sv * 64 + q * 8);
        x = x > 0.f ? x : SLOPE * x;
        float wg = __expf(x);
        den += wg;
        acc[0] += wg * bf_lo(u.x); acc[1] += wg * bf_hi(u.x);
        acc[2] += wg * bf_lo(u.y); acc[3] += wg * bf_hi(u.y);
        acc[4] += wg * bf_lo(u.z); acc[5] += wg * bf_hi(u.z);
        acc[6] += wg * bf_lo(u.w); acc[7] += wg * bf_hi(u.w);
    }
    float inv = 1.f / (den + 1e-10f);
    float o[8];
    #pragma unroll
    for (int j = 0; j < 8; j++) o[j] = acc[j] * inv;
    // softmax over 64 classes spread across the 8-lane group (xor 1,2,4 stays in-group)
    float mx = o[0];
    #pragma unroll
    for (int j = 1; j < 8; j++) mx = fmaxf(mx, o[j]);
    mx = fmaxf(mx, __shfl_xor(mx, 1));
    mx = fmaxf(mx, __shfl_xor(mx, 2));
    mx = fmaxf(mx, __shfl_xor(mx, 4));
    float e8[8], sm = 0.f;
    #pragma unroll
    for (int j = 0; j < 8; j++) { e8[j] = __expf(o[j] - mx); sm += e8[j]; }
    sm += __shfl_xor(sm, 1);
    sm += __shfl_xor(sm, 2);
    sm += __shfl_xor(sm, 4);
    float inv2 = 1.f / sm;
    float4* op = (float4*)(out + (size_t)n * 64 + q * 8);
    op[0] = make_float4(e8[0] * inv2, e8[1] * inv2, e8[2] * inv2, e8[3] * inv2);
    op[1] = make_float4(e8[4] * inv2, e8[5] * inv2, e8[6] * inv2, e8[7] * inv2);
}

// ---------------- launcher (4 dispatches + tiny memset) ----------------
extern "C" void kernel_launch(void* const* d_in, const int* in_sizes, int n_in,
                              void* d_out, int out_size, void* d_ws, size_t ws_size,
                              hipStream_t stream) {
    const float* X   = (const float*)d_in[0];
    const float* W1  = (const float*)d_in[1];
    const float* a1s = (const float*)d_in[2];
    const float* a1d = (const float*)d_in[3];
    const float* W2  = (const float*)d_in[4];
    const float* a2s = (const float*)d_in[5];
    const float* a2d = (const float*)d_in[6];
    const int*   src = (const int*)d_in[7];
    const int*   dst = (const int*)d_in[8];
    float* out = (float*)d_out;

    char* w = (char*)d_ws;
    size_t off = 0;
    auto alloc = [&](size_t bytes) {
        void* p = w + off;
        off += (bytes + 255) & ~(size_t)255;
        return p;
    };
    unsigned short* Bh   = (unsigned short*)alloc((size_t)C1 * F_IN * 2);
    unsigned short* Bl   = (unsigned short*)alloc((size_t)C1 * F_IN * 2);
    float*          es1  = (float*)alloc((size_t)N_NODES * 8 * 4);
    unsigned short* wh1  = (unsigned short*)alloc((size_t)N_NODES * 64 * 2);
    float*          es2  = (float*)alloc((size_t)N_NODES * 4);
    unsigned short* wh2  = (unsigned short*)alloc((size_t)N_NODES * 64 * 2);
    float*          ed1  = (float*)alloc((size_t)N_NODES * 8 * 4);
    float*          ed2  = (float*)alloc((size_t)N_NODES * 4);
    int*            deg  = (int*)alloc((size_t)N_NODES * 4);
    unsigned short* colPad = (unsigned short*)alloc((size_t)N_NODES * MAXDEG * 2);
    unsigned*       ebuf = (unsigned*)alloc((size_t)NBIN * BINCAP * 4);
    int*            gctr = (int*)alloc((size_t)NBIN * 4);

    hipMemsetAsync(gctr, 0, NBIN * 4, stream);

    k_prepbin<<<NBLK_WT + NBLK_E, 256, 0, stream>>>(W1, Bh, Bl, src, dst, ebuf, gctr);
    k_g1csr<<<NBIN + NBLK_G1, 256, 0, stream>>>(X, Bh, Bl, a1s, a1d, es1, wh1, ed1,
                                                ebuf, gctr, deg, colPad);
    k_agg1g2<<<NCHUNK, 256, 0, stream>>>(es1, wh1, ed1, deg, colPad,
                                         W2, a2s, a2d, es2, wh2, ed2);
    k_agg2<<<NCHUNK, 256, 0, stream>>>(es2, wh2, ed2, deg, colPad, out);
}